// Round 7
// baseline (51.939 us; speedup 1.0000x reference)
//
#include <hip/hip_runtime.h>

// Problem constants (match reference setup_inputs)
constexpr int BATCH = 16;
constexpr int NA = 2048;
constexpr int NB = 2048;
constexpr int THREADS = 256;
constexpr int ROWS_PER_BLOCK = 32;
constexpr int BLOCKS_PER_BATCH = NA / ROWS_PER_BLOCK;  // 64
constexpr int NACC = 11;

typedef float f32x4 __attribute__((ext_vector_type(4)));

// Accumulator index map:
// 0:S1  1:Sxb  2:Syb  3:Sqb  4:Sxa  5:Sya  6:Sqa
// 7:Sxaxb  8:Syayb  9:Syaxb  10:Sxayb
//
// Q assembly is linear in these 11 sums, so each block adds its own 5x5
// contribution directly into out via device-scope atomics (no fences, no
// second dispatch). d_out is zeroed by a memset node each call.
__global__ __launch_bounds__(THREADS) void pose_fused_atomic(
    const float* __restrict__ A,
    const float* __restrict__ pa,
    const float* __restrict__ pb,
    float* __restrict__ out)
{
    const int blk  = blockIdx.x;
    const int b    = blk / BLOCKS_PER_BATCH;
    const int rblk = blk - b * BLOCKS_PER_BATCH;
    const int t    = threadIdx.x;

    // Fixed columns for this thread: 4 at j0, 4 at j1 (NB=2048, 256 thr)
    const int j0 = t * 4;
    const int j1 = NB / 2 + t * 4;

    // Coefficients live in registers for the whole kernel.
    const float* pbb = pb + (size_t)b * NB * 2;  // interleaved (x,y)
    float xb[8], yb[8], qb[8];
    {
        f32x4 p0 = *(const f32x4*)(pbb + (size_t)j0 * 2);
        f32x4 p1 = *(const f32x4*)(pbb + (size_t)j0 * 2 + 4);
        f32x4 p2 = *(const f32x4*)(pbb + (size_t)j1 * 2);
        f32x4 p3 = *(const f32x4*)(pbb + (size_t)j1 * 2 + 4);
        xb[0] = p0.x; yb[0] = p0.y; xb[1] = p0.z; yb[1] = p0.w;
        xb[2] = p1.x; yb[2] = p1.y; xb[3] = p1.z; yb[3] = p1.w;
        xb[4] = p2.x; yb[4] = p2.y; xb[5] = p2.z; yb[5] = p2.w;
        xb[6] = p3.x; yb[6] = p3.y; xb[7] = p3.z; yb[7] = p3.w;
#pragma unroll
        for (int e = 0; e < 8; ++e) qb[e] = xb[e] * xb[e] + yb[e] * yb[e];
    }

    float acc[NACC];
#pragma unroll
    for (int k = 0; k < NACC; ++k) acc[k] = 0.f;

    const float* paa = pa + (size_t)b * NA * 2;  // interleaved (x,y)
    const int row0 = rblk * ROWS_PER_BLOCK;
    const float* arow_base = A + ((size_t)b * NA + row0) * NB;

#pragma unroll 8
    for (int r = 0; r < ROWS_PER_BLOCK; ++r) {
        const float* arow = arow_base + (size_t)r * NB;
        f32x4 a0 = *(const f32x4*)(arow + j0);
        f32x4 a1 = *(const f32x4*)(arow + j1);
        float xa = paa[(row0 + r) * 2];
        float ya = paa[(row0 + r) * 2 + 1];

        float av[8] = {a0.x, a0.y, a0.z, a0.w, a1.x, a1.y, a1.z, a1.w};
        float rS = 0.f, rX = 0.f, rY = 0.f, rQ = 0.f;
#pragma unroll
        for (int e = 0; e < 8; ++e) {
            rS += av[e];
            rX += av[e] * xb[e];
            rY += av[e] * yb[e];
            rQ += av[e] * qb[e];
        }
        acc[0] += rS;
        acc[1] += rX;
        acc[2] += rY;
        acc[3] += rQ;
        acc[4] += xa * rS;
        acc[5] += ya * rS;
        acc[6] += (xa * xa + ya * ya) * rS;
        acc[7] += xa * rX;
        acc[8] += ya * rY;
        acc[9] += ya * rX;
        acc[10] += xa * rY;
    }

    // Block reduction: wave shuffle then cross-wave via LDS.
    __shared__ float red[THREADS / 64][NACC];
    const int lane = t & 63, wv = t >> 6;
#pragma unroll
    for (int k = 0; k < NACC; ++k) {
        float v = acc[k];
        for (int off = 32; off > 0; off >>= 1) v += __shfl_down(v, off, 64);
        if (lane == 0) red[wv][k] = v;
    }
    __syncthreads();

    // Assemble this block's 5x5 contribution and atomically add into out.
    __shared__ float qv[25];
    if (t == 0) {
        float s[NACC];
#pragma unroll
        for (int k = 0; k < NACC; ++k)
            s[k] = red[0][k] + red[1][k] + red[2][k] + red[3][k];
        float S1 = s[0], Sxb = s[1], Syb = s[2], Sqb = s[3];
        float Sxa = s[4], Sya = s[5], Sqa = s[6];
        float Sxaxb = s[7], Syayb = s[8], Syaxb = s[9], Sxayb = s[10];
        float q00 = Sqb, q01 = -Sxb, q02 = -Syb;
        float q03 = -(Sxaxb + Syayb), q04 = Syaxb - Sxayb;
        float w = S1, q13 = Sxa, q14 = -Sya, q23 = Sya, q24 = Sxa, q33 = Sqa;
        qv[0] = q00;  qv[1] = q01;  qv[2] = q02;  qv[3] = q03;  qv[4] = q04;
        qv[5] = q01;  qv[6] = w;    qv[7] = 0.f;  qv[8] = q13;  qv[9] = q14;
        qv[10] = q02; qv[11] = 0.f; qv[12] = w;   qv[13] = q23; qv[14] = q24;
        qv[15] = q03; qv[16] = q13; qv[17] = q23; qv[18] = q33; qv[19] = 0.f;
        qv[20] = q04; qv[21] = q14; qv[22] = q24; qv[23] = 0.f; qv[24] = q33;
    }
    __syncthreads();
    if (t < 25) atomicAdd(&out[b * 25 + t], qv[t]);
}

extern "C" void kernel_launch(void* const* d_in, const int* in_sizes, int n_in,
                              void* d_out, int out_size, void* d_ws, size_t ws_size,
                              hipStream_t stream) {
    const float* A  = (const float*)d_in[0];   // (B, Na, Nb)
    const float* pa = (const float*)d_in[1];   // (B, Na, 2)
    const float* pb = (const float*)d_in[2];   // (B, Nb, 2)
    float* out = (float*)d_out;                // (B, 5, 5)

    // Zero output each call (harness does not re-poison between replays).
    hipMemsetAsync(out, 0, sizeof(float) * BATCH * 25, stream);

    pose_fused_atomic<<<BATCH * BLOCKS_PER_BATCH, THREADS, 0, stream>>>(
        A, pa, pb, out);
}

// Round 8
// 49.580 us; speedup vs baseline: 1.0476x; 1.0476x over previous
//
#include <hip/hip_runtime.h>

// Problem constants (match reference setup_inputs)
constexpr int BATCH = 16;
constexpr int NA = 2048;
constexpr int NB = 2048;
constexpr int THREADS = 256;
constexpr int ROWS_PER_BLOCK = 16;
constexpr int BLOCKS_PER_BATCH = NA / ROWS_PER_BLOCK;  // 128
constexpr int NACC = 11;

typedef float f32x4 __attribute__((ext_vector_type(4)));

// Accumulator index map:
// 0:S1  1:Sxb  2:Syb  3:Sqb  4:Sxa  5:Sya  6:Sqa
// 7:Sxaxb  8:Syayb  9:Syaxb  10:Sxayb
__global__ __launch_bounds__(THREADS) void pose_partial(
    const float* __restrict__ A,
    const float* __restrict__ pa,
    const float* __restrict__ pb,
    float* __restrict__ partial)
{
    const int blk  = blockIdx.x;
    const int b    = blk / BLOCKS_PER_BATCH;
    const int rblk = blk - b * BLOCKS_PER_BATCH;
    const int t    = threadIdx.x;

    // Fixed columns for this thread: 4 at j0, 4 at j1 (NB=2048, 256 thr)
    const int j0 = t * 4;
    const int j1 = NB / 2 + t * 4;

    // Coefficients live in registers for the whole kernel.
    const float* pbb = pb + (size_t)b * NB * 2;  // interleaved (x,y)
    float xb[8], yb[8], qb[8];
    {
        f32x4 p0 = *(const f32x4*)(pbb + (size_t)j0 * 2);
        f32x4 p1 = *(const f32x4*)(pbb + (size_t)j0 * 2 + 4);
        f32x4 p2 = *(const f32x4*)(pbb + (size_t)j1 * 2);
        f32x4 p3 = *(const f32x4*)(pbb + (size_t)j1 * 2 + 4);
        xb[0] = p0.x; yb[0] = p0.y; xb[1] = p0.z; yb[1] = p0.w;
        xb[2] = p1.x; yb[2] = p1.y; xb[3] = p1.z; yb[3] = p1.w;
        xb[4] = p2.x; yb[4] = p2.y; xb[5] = p2.z; yb[5] = p2.w;
        xb[6] = p3.x; yb[6] = p3.y; xb[7] = p3.z; yb[7] = p3.w;
#pragma unroll
        for (int e = 0; e < 8; ++e) qb[e] = xb[e] * xb[e] + yb[e] * yb[e];
    }

    float acc[NACC];
#pragma unroll
    for (int k = 0; k < NACC; ++k) acc[k] = 0.f;

    const float* paa = pa + (size_t)b * NA * 2;  // interleaved (x,y)
    const int row0 = rblk * ROWS_PER_BLOCK;
    const float* arow_base = A + ((size_t)b * NA + row0) * NB;

    // Explicit 2-stage software pipeline: prefetch row r+1 while
    // accumulating row r (R7 post-mortem: compiler kept VGPR=40 and only
    // ~4-6 loads in flight; force deeper MLP).
    f32x4 c0 = *(const f32x4*)(arow_base + j0);
    f32x4 c1 = *(const f32x4*)(arow_base + j1);

#define ACCUM(r_, v0_, v1_)                                                  \
    do {                                                                     \
        float xa = paa[(row0 + (r_)) * 2];                                   \
        float ya = paa[(row0 + (r_)) * 2 + 1];                               \
        float av[8] = {v0_.x, v0_.y, v0_.z, v0_.w,                           \
                       v1_.x, v1_.y, v1_.z, v1_.w};                          \
        float rS = 0.f, rX = 0.f, rY = 0.f, rQ = 0.f;                        \
        _Pragma("unroll")                                                    \
        for (int e = 0; e < 8; ++e) {                                        \
            rS += av[e];                                                     \
            rX += av[e] * xb[e];                                             \
            rY += av[e] * yb[e];                                             \
            rQ += av[e] * qb[e];                                             \
        }                                                                    \
        acc[0] += rS;                                                        \
        acc[1] += rX;                                                        \
        acc[2] += rY;                                                        \
        acc[3] += rQ;                                                        \
        acc[4] += xa * rS;                                                   \
        acc[5] += ya * rS;                                                   \
        acc[6] += (xa * xa + ya * ya) * rS;                                  \
        acc[7] += xa * rX;                                                   \
        acc[8] += ya * rY;                                                   \
        acc[9] += ya * rX;                                                   \
        acc[10] += xa * rY;                                                  \
    } while (0)

#pragma unroll 5
    for (int r = 0; r < ROWS_PER_BLOCK - 1; ++r) {
        const float* nrow = arow_base + (size_t)(r + 1) * NB;
        f32x4 n0 = *(const f32x4*)(nrow + j0);
        f32x4 n1 = *(const f32x4*)(nrow + j1);
        ACCUM(r, c0, c1);
        c0 = n0;
        c1 = n1;
    }
    ACCUM(ROWS_PER_BLOCK - 1, c0, c1);
#undef ACCUM

    // Block reduction: wave shuffle then cross-wave via LDS.
    __shared__ float red[THREADS / 64][NACC];
    const int lane = t & 63, wv = t >> 6;
#pragma unroll
    for (int k = 0; k < NACC; ++k) {
        float v = acc[k];
        for (int off = 32; off > 0; off >>= 1) v += __shfl_down(v, off, 64);
        if (lane == 0) red[wv][k] = v;
    }
    __syncthreads();
    if (t < NACC) {
        partial[(size_t)blk * NACC + t] =
            red[0][t] + red[1][t] + red[2][t] + red[3][t];
    }
}

// Parallel finalize: one thread per source partial block (128 per batch).
__global__ __launch_bounds__(128) void pose_finalize(
    const float* __restrict__ partial, float* __restrict__ out)
{
    const int b = blockIdx.x;
    const int t = threadIdx.x;          // 0..127, one per partial block
    const int lane = t & 63, wv = t >> 6;

    float v[NACC];
    const float* p = partial + ((size_t)b * BLOCKS_PER_BATCH + t) * NACC;
#pragma unroll
    for (int k = 0; k < NACC; ++k) v[k] = p[k];

#pragma unroll
    for (int k = 0; k < NACC; ++k) {
        for (int off = 32; off > 0; off >>= 1) v[k] += __shfl_down(v[k], off, 64);
    }

    __shared__ float red[2][NACC];
    if (lane == 0) {
#pragma unroll
        for (int k = 0; k < NACC; ++k) red[wv][k] = v[k];
    }
    __syncthreads();

    __shared__ float qm[25];
    if (t == 0) {
        float s[NACC];
#pragma unroll
        for (int k = 0; k < NACC; ++k) s[k] = red[0][k] + red[1][k];
        float S1 = s[0], Sxb = s[1], Syb = s[2], Sqb = s[3];
        float Sxa = s[4], Sya = s[5], Sqa = s[6];
        float Sxaxb = s[7], Syayb = s[8], Syaxb = s[9], Sxayb = s[10];
        float q00 = Sqb, q01 = -Sxb, q02 = -Syb;
        float q03 = -(Sxaxb + Syayb), q04 = Syaxb - Sxayb;
        float w = S1, q13 = Sxa, q14 = -Sya, q23 = Sya, q24 = Sxa, q33 = Sqa;
        qm[0] = q00; qm[1] = q01; qm[2] = q02; qm[3] = q03; qm[4] = q04;
        qm[5] = q01; qm[6] = w;   qm[7] = 0.f; qm[8] = q13; qm[9] = q14;
        qm[10] = q02; qm[11] = 0.f; qm[12] = w;  qm[13] = q23; qm[14] = q24;
        qm[15] = q03; qm[16] = q13; qm[17] = q23; qm[18] = q33; qm[19] = 0.f;
        qm[20] = q04; qm[21] = q14; qm[22] = q24; qm[23] = 0.f; qm[24] = q33;
    }
    __syncthreads();
    if (t < 25) out[b * 25 + t] = qm[t];
}

extern "C" void kernel_launch(void* const* d_in, const int* in_sizes, int n_in,
                              void* d_out, int out_size, void* d_ws, size_t ws_size,
                              hipStream_t stream) {
    const float* A  = (const float*)d_in[0];   // (B, Na, Nb)
    const float* pa = (const float*)d_in[1];   // (B, Na, 2)
    const float* pb = (const float*)d_in[2];   // (B, Nb, 2)
    float* out = (float*)d_out;                // (B, 5, 5)
    float* partial = (float*)d_ws;             // BATCH*BLOCKS_PER_BATCH*NACC floats

    pose_partial<<<BATCH * BLOCKS_PER_BATCH, THREADS, 0, stream>>>(A, pa, pb, partial);
    pose_finalize<<<BATCH, 128, 0, stream>>>(partial, out);
}

// Round 9
// 48.316 us; speedup vs baseline: 1.0750x; 1.0262x over previous
//
#include <hip/hip_runtime.h>

// Problem constants (match reference setup_inputs)
constexpr int BATCH = 16;
constexpr int NA = 2048;
constexpr int NB = 2048;
constexpr int THREADS = 256;
constexpr int ROWS_PER_BLOCK = 32;
constexpr int BLOCKS_PER_BATCH = NA / ROWS_PER_BLOCK;  // 64
constexpr int NACC = 11;

typedef float f32x4 __attribute__((ext_vector_type(4)));

// Best measured configuration (R6: 48.5 us):
//  - 2-dispatch structure (fence-fusion R5: 3x regression; atomic-fusion R7: +3.4us)
//  - plain loads (nt loads: no gain, R4 vs R6)
//  - 32 rows/block -> 1024 blocks = 4/CU (16 rows / 8 blocks/CU: no gain, R8)
//  - compiler-scheduled loads (explicit SW pipeline: no gain, R8)
// Main kernel ~5.84 TB/s ~= 93% of measured read ceiling (m13: 6.29 TB/s).
//
// Accumulator index map:
// 0:S1  1:Sxb  2:Syb  3:Sqb  4:Sxa  5:Sya  6:Sqa
// 7:Sxaxb  8:Syayb  9:Syaxb  10:Sxayb
__global__ __launch_bounds__(THREADS) void pose_partial(
    const float* __restrict__ A,
    const float* __restrict__ pa,
    const float* __restrict__ pb,
    float* __restrict__ partial)
{
    const int blk  = blockIdx.x;
    const int b    = blk / BLOCKS_PER_BATCH;
    const int rblk = blk - b * BLOCKS_PER_BATCH;
    const int t    = threadIdx.x;

    // Fixed columns for this thread: 4 at j0, 4 at j1 (NB=2048, 256 thr)
    const int j0 = t * 4;
    const int j1 = NB / 2 + t * 4;

    // Coefficients live in registers for the whole kernel.
    const float* pbb = pb + (size_t)b * NB * 2;  // interleaved (x,y)
    float xb[8], yb[8], qb[8];
    {
        f32x4 p0 = *(const f32x4*)(pbb + (size_t)j0 * 2);
        f32x4 p1 = *(const f32x4*)(pbb + (size_t)j0 * 2 + 4);
        f32x4 p2 = *(const f32x4*)(pbb + (size_t)j1 * 2);
        f32x4 p3 = *(const f32x4*)(pbb + (size_t)j1 * 2 + 4);
        xb[0] = p0.x; yb[0] = p0.y; xb[1] = p0.z; yb[1] = p0.w;
        xb[2] = p1.x; yb[2] = p1.y; xb[3] = p1.z; yb[3] = p1.w;
        xb[4] = p2.x; yb[4] = p2.y; xb[5] = p2.z; yb[5] = p2.w;
        xb[6] = p3.x; yb[6] = p3.y; xb[7] = p3.z; yb[7] = p3.w;
#pragma unroll
        for (int e = 0; e < 8; ++e) qb[e] = xb[e] * xb[e] + yb[e] * yb[e];
    }

    float acc[NACC];
#pragma unroll
    for (int k = 0; k < NACC; ++k) acc[k] = 0.f;

    const float* paa = pa + (size_t)b * NA * 2;  // interleaved (x,y)
    const int row0 = rblk * ROWS_PER_BLOCK;
    const float* arow_base = A + ((size_t)b * NA + row0) * NB;

#pragma unroll 8
    for (int r = 0; r < ROWS_PER_BLOCK; ++r) {
        const float* arow = arow_base + (size_t)r * NB;
        f32x4 a0 = *(const f32x4*)(arow + j0);
        f32x4 a1 = *(const f32x4*)(arow + j1);
        float xa = paa[(row0 + r) * 2];
        float ya = paa[(row0 + r) * 2 + 1];

        float av[8] = {a0.x, a0.y, a0.z, a0.w, a1.x, a1.y, a1.z, a1.w};
        float rS = 0.f, rX = 0.f, rY = 0.f, rQ = 0.f;
#pragma unroll
        for (int e = 0; e < 8; ++e) {
            rS += av[e];
            rX += av[e] * xb[e];
            rY += av[e] * yb[e];
            rQ += av[e] * qb[e];
        }
        acc[0] += rS;
        acc[1] += rX;
        acc[2] += rY;
        acc[3] += rQ;
        acc[4] += xa * rS;
        acc[5] += ya * rS;
        acc[6] += (xa * xa + ya * ya) * rS;
        acc[7] += xa * rX;
        acc[8] += ya * rY;
        acc[9] += ya * rX;
        acc[10] += xa * rY;
    }

    // Block reduction: wave shuffle then cross-wave via LDS.
    __shared__ float red[THREADS / 64][NACC];
    const int lane = t & 63, wv = t >> 6;
#pragma unroll
    for (int k = 0; k < NACC; ++k) {
        float v = acc[k];
        for (int off = 32; off > 0; off >>= 1) v += __shfl_down(v, off, 64);
        if (lane == 0) red[wv][k] = v;
    }
    __syncthreads();
    if (t < NACC) {
        partial[(size_t)blk * NACC + t] =
            red[0][t] + red[1][t] + red[2][t] + red[3][t];
    }
}

// Parallel finalize: one wave per batch, one thread per source partial block.
__global__ __launch_bounds__(64) void pose_finalize(
    const float* __restrict__ partial, float* __restrict__ out)
{
    const int b = blockIdx.x;
    const int t = threadIdx.x;          // 0..63, one per partial block

    float v[NACC];
    const float* p = partial + ((size_t)b * BLOCKS_PER_BATCH + t) * NACC;
#pragma unroll
    for (int k = 0; k < NACC; ++k) v[k] = p[k];

#pragma unroll
    for (int k = 0; k < NACC; ++k) {
        for (int off = 32; off > 0; off >>= 1) v[k] += __shfl_down(v[k], off, 64);
    }

    __shared__ float qm[25];
    if (t == 0) {
        float S1 = v[0], Sxb = v[1], Syb = v[2], Sqb = v[3];
        float Sxa = v[4], Sya = v[5], Sqa = v[6];
        float Sxaxb = v[7], Syayb = v[8], Syaxb = v[9], Sxayb = v[10];
        float q00 = Sqb, q01 = -Sxb, q02 = -Syb;
        float q03 = -(Sxaxb + Syayb), q04 = Syaxb - Sxayb;
        float w = S1, q13 = Sxa, q14 = -Sya, q23 = Sya, q24 = Sxa, q33 = Sqa;
        qm[0] = q00; qm[1] = q01; qm[2] = q02; qm[3] = q03; qm[4] = q04;
        qm[5] = q01; qm[6] = w;   qm[7] = 0.f; qm[8] = q13; qm[9] = q14;
        qm[10] = q02; qm[11] = 0.f; qm[12] = w;  qm[13] = q23; qm[14] = q24;
        qm[15] = q03; qm[16] = q13; qm[17] = q23; qm[18] = q33; qm[19] = 0.f;
        qm[20] = q04; qm[21] = q14; qm[22] = q24; qm[23] = 0.f; qm[24] = q33;
    }
    __syncthreads();
    if (t < 25) out[b * 25 + t] = qm[t];
}

extern "C" void kernel_launch(void* const* d_in, const int* in_sizes, int n_in,
                              void* d_out, int out_size, void* d_ws, size_t ws_size,
                              hipStream_t stream) {
    const float* A  = (const float*)d_in[0];   // (B, Na, Nb)
    const float* pa = (const float*)d_in[1];   // (B, Na, 2)
    const float* pb = (const float*)d_in[2];   // (B, Nb, 2)
    float* out = (float*)d_out;                // (B, 5, 5)
    float* partial = (float*)d_ws;             // BATCH*BLOCKS_PER_BATCH*NACC floats

    pose_partial<<<BATCH * BLOCKS_PER_BATCH, THREADS, 0, stream>>>(A, pa, pb, partial);
    pose_finalize<<<BATCH, 64, 0, stream>>>(partial, out);
}